// Round 19
// baseline (388.879 us; speedup 1.0000x reference)
//
#include <hip/hip_runtime.h>
#include <hip/hip_bf16.h>

#define S_LEN 2048
#define NH    16
#define HD    128
#define BHN   32      // B * NH
#define DM    2048
#define MTOK  4096    // B * S
#define NTK   32      // K / 64

typedef __attribute__((ext_vector_type(8))) short short8;
typedef __attribute__((ext_vector_type(4))) float f32x4;

__device__ __forceinline__ unsigned short f2bf(float x){
  union { __hip_bfloat16 h; unsigned short u; } c; c.h = __float2bfloat16(x); return c.u;
}
__device__ __forceinline__ float bf2f(unsigned short u){
  union { unsigned short u; __hip_bfloat16 h; } c; c.u = u; return __bfloat162float(c.h);
}

// ---------------- fused prep: hs cvt + 4 weight cvts (Q/K rows rope-permuted) + rope table ----
__global__ void prep_kernel(const float* __restrict__ hs, const float* __restrict__ Wq,
                            const float* __restrict__ Wk, const float* __restrict__ Wv,
                            const float* __restrict__ Wo,
                            unsigned short* __restrict__ hsb, unsigned short* __restrict__ wqkv,
                            unsigned short* __restrict__ wob,
                            float* __restrict__ cosT, float* __restrict__ sinT){
  const int NH4 = MTOK*DM/4;
  const int NW4 = DM*DM/4;
  int gid = blockIdx.x*256 + threadIdx.x;
  if (gid < NH4){
    float4 v = reinterpret_cast<const float4*>(hs)[gid];
    ushort4 o;
    o.x = f2bf(v.x); o.y = f2bf(v.y); o.z = f2bf(v.z); o.w = f2bf(v.w);
    reinterpret_cast<ushort4*>(hsb)[gid] = o;
  } else if (gid < NH4 + 4*NW4){
    int k = gid - NH4;
    int which = k >> 20, j = k & (NW4 - 1);
    const float* src = (which==0) ? Wq : (which==1) ? Wk : (which==2) ? Wv : Wo;
    float4 v = reinterpret_cast<const float4*>(src)[j];
    ushort4 o;
    o.x = f2bf(v.x); o.y = f2bf(v.y); o.z = f2bf(v.z); o.w = f2bf(v.w);
    int row = j >> 9, cc = j & 511;
    int drow = row;
    if (which < 2){                    // rope-permute Q and K rows
      int d = row & 127;
      int d2 = (d < 64) ? (d << 1) : (((d - 64) << 1) | 1);
      drow = (row & ~127) | d2;
    }
    if (which < 3)
      reinterpret_cast<ushort4*>(wqkv)[((size_t)which << 20) + drow*512 + cc] = o;
    else
      reinterpret_cast<ushort4*>(wob)[drow*512 + cc] = o;
  } else {
    int k = gid - NH4 - 4*NW4;
    if (k < S_LEN*64){
      int s = k >> 6, i = k & 63;
      float inv = powf(10000.f, -(float)i * (1.f/64.f));
      float ph = (float)s * inv;
      float sv, cv; sincosf(ph, &sv, &cv);
      cosT[k] = cv; sinT[k] = sv;
    }
  }
}

// ============ 128xBN whole-tile-dbuf GEMM, K=2048 ============
// MODE 3 (QKV): BN=192, LDS 80KB -> 2 blocks/CU, grid 1024 (R17: MfmaUtil 45%).
// MODE 0 (Wo): BN=256, LDS 96KB, grid 256 = 1 round (R15 proven).
template<int MODE>
__global__ __launch_bounds__(512)
void gemm_2ph(const unsigned short* __restrict__ A, const unsigned short* __restrict__ B,
              float* __restrict__ C0, unsigned short* __restrict__ Cq,
              unsigned short* __restrict__ Ck, unsigned short* __restrict__ Cv,
              const float* __restrict__ cosT, const float* __restrict__ sinT){
  constexpr int BN   = (MODE==3) ? 192 : 256;
  constexpr int NJ   = BN/64;
  constexpr int BUFSZ = 16384 + BN*128;
  extern __shared__ unsigned char sm[];
  const int t = threadIdx.x;
  const int lane = t & 63, w = t >> 6;
  const int lr = lane & 15, lg = lane >> 4;
  const int wm = w >> 2, wn = w & 3;
  int bm, bn;
  if (MODE == 3){ int swz = (blockIdx.x & 7)*128 + (blockIdx.x >> 3);
                  bm = swz & 31; bn = swz >> 5; }
  else          { bn = blockIdx.x & 7; bm = blockIdx.x >> 3; }
  const size_t rs = 4096;
  const unsigned char* Ab = (const unsigned char*)A + (size_t)bm*128*rs;
  const unsigned char* Bb = (const unsigned char*)B + (size_t)bn*BN*rs;
  const int r0 = t >> 3, c0 = t & 7;
  const int cs = (c0 ^ (r0 & 7)) << 4;

  auto stage = [&](int tkt){
    if (tkt >= NTK) return;
    unsigned char* hb = sm + (tkt & 1)*BUFSZ;
    const unsigned char* Bt = Bb + (size_t)tkt*128;
#pragma unroll
    for (int j=0;j<NJ;++j)
      __builtin_amdgcn_global_load_lds((const unsigned int*)(Bt + (size_t)(r0+64*j)*rs + cs),
          (unsigned int*)(hb + 16384 + (size_t)(t + 512*j)*16), 16, 0, 0);
    const unsigned char* At = Ab + (size_t)tkt*128;
    __builtin_amdgcn_global_load_lds((const unsigned int*)(At + (size_t)r0*rs + cs),
        (unsigned int*)(hb + t*16), 16, 0, 0);
    __builtin_amdgcn_global_load_lds((const unsigned int*)(At + (size_t)(r0+64)*rs + cs),
        (unsigned int*)(hb + 8192 + t*16), 16, 0, 0);
  };

  f32x4 acc[4][NJ] = {};

  stage(0);
  asm volatile("s_waitcnt vmcnt(0)" ::: "memory");
  __builtin_amdgcn_s_barrier();

  for (int g = 0; g < NTK; ++g){
    stage(g+1);
    const unsigned char* hb = sm + (g & 1)*BUFSZ;
    short8 af[8];
#pragma unroll
    for (int mi=0;mi<4;++mi){
      int row = wm*64 + mi*16 + lr;
      const unsigned char* rp = hb + row*128;
      int x = (row & 7) << 4;
#pragma unroll
      for (int ks=0;ks<2;++ks)
        af[mi*2+ks] = *reinterpret_cast<const short8*>(rp + (((ks*4+lg) << 4) ^ x));
    }
    short8 bfr[NJ*2];
#pragma unroll
    for (int nj=0;nj<NJ;++nj){
      int row = wn*(BN/4) + nj*16 + lr;
      const unsigned char* rp = hb + 16384 + row*128;
      int x = (row & 7) << 4;
#pragma unroll
      for (int ks=0;ks<2;++ks)
        bfr[nj*2+ks] = *reinterpret_cast<const short8*>(rp + (((ks*4+lg) << 4) ^ x));
    }
    __builtin_amdgcn_s_setprio(1);
#pragma unroll
    for (int mi=0;mi<4;++mi)
#pragma unroll
      for (int nj=0;nj<NJ;++nj){
        acc[mi][nj] = __builtin_amdgcn_mfma_f32_16x16x32_bf16(af[mi*2+0], bfr[nj*2+0], acc[mi][nj], 0,0,0);
        acc[mi][nj] = __builtin_amdgcn_mfma_f32_16x16x32_bf16(af[mi*2+1], bfr[nj*2+1], acc[mi][nj], 0,0,0);
      }
    __builtin_amdgcn_s_setprio(0);
    asm volatile("s_waitcnt vmcnt(0)" ::: "memory");
    __builtin_amdgcn_s_barrier();
  }

  if (MODE == 0){
#pragma unroll
    for (int mi=0;mi<4;++mi)
#pragma unroll
      for (int nj=0;nj<NJ;++nj){
        int col  = bn*BN + wn*(BN/4) + nj*16 + lr;
        int rowb = bm*128 + wm*64 + mi*16 + lg*4;
#pragma unroll
        for (int rr=0;rr<4;++rr)
          C0[(size_t)(rowb+rr)*DM + col] = acc[mi][nj][rr];
      }
  } else {
#pragma unroll
    for (int mi=0;mi<4;++mi)
#pragma unroll
      for (int nj=0;nj<NJ;++nj){
        int col  = bn*BN + wn*(BN/4) + nj*16 + lr;
        int rowb = bm*128 + wm*64 + mi*16 + lg*4;
        if (col >= 4096){
          int cc = col - 4096, h = cc >> 7, dd = cc & 127;
          ushort4 pk;
          pk.x = f2bf(acc[mi][nj][0]); pk.y = f2bf(acc[mi][nj][1]);
          pk.z = f2bf(acc[mi][nj][2]); pk.w = f2bf(acc[mi][nj][3]);
          int bb = rowb >> 11, s = rowb & 2047, kb = s >> 6, kvl = s & 63;
          *reinterpret_cast<ushort4*>(&Cv[(((size_t)((bb*16+h)*32 + kb)*128 + dd)<<6) + kvl]) = pk;
        }
      }
    const int qkCols = (bn*BN < 4096) ? ((4096 - bn*BN < BN) ? (4096 - bn*BN) : BN) : 0;
    if (qkCols > 0){
      unsigned short* S = reinterpret_cast<unsigned short*>(sm);
#pragma unroll
      for (int mi=0;mi<4;++mi)
#pragma unroll
        for (int nj=0;nj<NJ;++nj){
          int cl = wn*(BN/4) + nj*16 + lr;
          if (bn*BN + cl < 4096){
            int rl = wm*64 + mi*16 + lg*4;
#pragma unroll
            for (int rr=0;rr<4;++rr)
              S[(rl+rr)*200 + cl] = f2bf(acc[mi][nj][rr]);
          }
        }
      __syncthreads();
      const int nGrp  = qkCols >> 2;
      const int items = (128*nGrp) >> 9;
      for (int it=0; it<items; ++it){
        int idx = it*512 + t;
        int r = idx / nGrp, gq = idx - r*nGrp;
        int cl = gq*4;
        ushort4 v = *reinterpret_cast<const ushort4*>(&S[r*200 + cl]);
        int col = bn*BN + cl;
        int h = col >> 7, g = (col & 127) >> 2;
        int row = bm*128 + r, bb = row >> 11, s = row & 2047;
        const float* ct = cosT + s*64; const float* st = sinT + s*64;
        float cg = ct[g], sg = st[g], ch = ct[32+g], sh = st[32+g];
        float v0 = bf2f(v.x), v1 = bf2f(v.y), v2 = bf2f(v.z), v3 = bf2f(v.w);
        ushort4 o;
        o.x = f2bf(v0*cg - v1*sg);
        o.y = f2bf(v1*ch + v0*sh);
        o.z = f2bf(v2*cg - v3*sg);
        o.w = f2bf(v3*ch + v2*sh);
        unsigned short* dst = (h < 16) ? Cq : Ck;
        *reinterpret_cast<ushort4*>(&dst[(((size_t)(bb*16 + (h & 15))*2048 + s) << 7) + (col & 127)]) = o;
      }
    }
  }
}

// ---------------- causal softcap flash attention (direct-global K/V, barrier-free) ----------------
// K frag: 16 fully-used 64B lines/instr (rows 256B apart, 4 lanes x 16B per line).
// V frag (packed [bh][kb][128][64]): 16 fully-used lines (rows 128B, 64B halves).
// K+V per bh = 1MB, L2-resident; the 16 q-blocks per bh share it. No LDS staging,
// no __syncthreads: each wave loops to ITS OWN diagonal, TLP+vmcnt hide latency.
// P^T re-fragmentation stays in per-wave LDS (16KB static, XOR-swizzled).
__global__ __launch_bounds__(256)
void attn_kernel(const unsigned short* __restrict__ Qr, const unsigned short* __restrict__ Kr,
                 const unsigned short* __restrict__ Vp, unsigned short* __restrict__ AO){
  __shared__ __align__(16) unsigned char smP[16384];
  const int bid = blockIdx.x;                 // 512 = 16 qb * 32 bh
  const int qb  = (bid < 256) ? (15 - (bid >> 5)) : ((bid >> 5) - 8);
  const int bh  = bid & 31;
  const int t = threadIdx.x;
  const int w = t >> 6, lane = t & 63, lr = lane & 15, lg = lane >> 4;
  const int qbase = qb*128 + w*32;
  const int diag_w = (qbase + 31) >> 6;       // per-wave last kv tile
  const unsigned short* Qh = Qr + (size_t)bh*S_LEN*HD;
  const unsigned short* Kh = Kr + (size_t)bh*S_LEN*HD;
  const unsigned short* Vh = Vp + (size_t)bh*32*8192;   // packed tiles, 8192 elems each

  short8 qa[2][4];
#pragma unroll
  for (int f=0;f<2;++f)
#pragma unroll
    for (int kc=0;kc<4;++kc)
      qa[f][kc] = *reinterpret_cast<const short8*>(&Qh[(size_t)(qbase + f*16 + lr)*HD + kc*32 + lg*8]);

  float lsum[2] = {0.f, 0.f};
  f32x4 o[2][8] = {};

  const float PA = 0.12752783f;      // log2e*SCALE
  const float PB = -3.68975e-7f;     // -log2e*SCALE^3/2700
  const float PC = 1.28117e-12f;     // log2e*1.6460905e-7*SCALE^5
  const float PD = -43.2808512f;     // -30*log2e

  unsigned char* Psb = smP + w*4096;          // [32 rows][128B], XOR-swizzled

  for (int kb = 0; kb <= diag_w; ++kb){
    // --- QK^T: K fragments direct from global (L2-hot) ---
    f32x4 s[2][4] = {};
    __builtin_amdgcn_s_setprio(1);
#pragma unroll
    for (int nf=0;nf<4;++nf)
#pragma unroll
      for (int kc=0;kc<4;++kc){
        short8 kf = *reinterpret_cast<const short8*>(
            &Kh[(size_t)(kb*64 + nf*16 + lr)*HD + kc*32 + lg*8]);
        s[0][nf] = __builtin_amdgcn_mfma_f32_16x16x32_bf16(kf, qa[0][kc], s[0][nf], 0,0,0);
        s[1][nf] = __builtin_amdgcn_mfma_f32_16x16x32_bf16(kf, qa[1][kc], s[1][nf], 0,0,0);
      }
    __builtin_amdgcn_s_setprio(0);
    // --- softcap poly + causal + per-lane sum + P^T -> LDS ---
#pragma unroll
    for (int f=0;f<2;++f){
      const int prow = f*16 + lr;
      const unsigned int pswz = (unsigned int)(prow & 7) << 4;
#pragma unroll
      for (int nf=0;nf<4;++nf){
#pragma unroll
        for (int r=0;r<4;++r){
          float sv = s[f][nf][r];
          float u2 = sv*sv;
          float tt = fmaf(u2, PC, PB);
          tt = fmaf(u2, tt, PA);
          float p = __builtin_amdgcn_exp2f(fmaf(sv, tt, PD));
          if (kb == diag_w){
            int kvi = kb*64 + nf*16 + lg*4 + r;
            if (kvi > qbase + f*16 + lr) p = 0.f;
          }
          s[f][nf][r] = p;
          lsum[f] += p;
        }
        ushort4 pk;
        pk.x = f2bf(s[f][nf][0]); pk.y = f2bf(s[f][nf][1]);
        pk.z = f2bf(s[f][nf][2]); pk.w = f2bf(s[f][nf][3]);
        *reinterpret_cast<ushort4*>(Psb + prow*128 + (((unsigned int)(nf*32 + lg*8)) ^ pswz)) = pk;
      }
    }
    short8 pb[2][2];
#pragma unroll
    for (int f=0;f<2;++f){
      const int prow = f*16 + lr;
      const unsigned int pswz = (unsigned int)(prow & 7) << 4;
#pragma unroll
      for (int kc2=0;kc2<2;++kc2)
        pb[f][kc2] = *reinterpret_cast<const short8*>(Psb + prow*128 + (((unsigned int)(kc2*64 + lg*16)) ^ pswz));
    }
    // --- PV: V fragments direct from global (packed layout) ---
    const unsigned short* Vt = Vh + (size_t)kb*8192;
    __builtin_amdgcn_s_setprio(1);
#pragma unroll
    for (int df=0;df<8;++df)
#pragma unroll
      for (int kc2=0;kc2<2;++kc2){
        short8 vb = *reinterpret_cast<const short8*>(
            &Vt[(df*16+lr)*64 + kc2*32 + lg*8]);
        o[0][df] = __builtin_amdgcn_mfma_f32_16x16x32_bf16(vb, pb[0][kc2], o[0][df], 0,0,0);
        o[1][df] = __builtin_amdgcn_mfma_f32_16x16x32_bf16(vb, pb[1][kc2], o[1][df], 0,0,0);
      }
    __builtin_amdgcn_s_setprio(0);
  }
#pragma unroll
  for (int f=0;f<2;++f){
    lsum[f] += __shfl_xor(lsum[f], 16);
    lsum[f] += __shfl_xor(lsum[f], 32);
  }
  const int bb = bh >> 4, h = bh & 15;
#pragma unroll
  for (int f=0;f<2;++f){
    const float inv = 1.f / lsum[f];
    const int qi = qbase + f*16 + lr;
#pragma unroll
    for (int df=0;df<8;++df){
      ushort4 pk;
      pk.x = f2bf(o[f][df][0] * inv); pk.y = f2bf(o[f][df][1] * inv);
      pk.z = f2bf(o[f][df][2] * inv); pk.w = f2bf(o[f][df][3] * inv);
      *reinterpret_cast<ushort4*>(&AO[((size_t)(bb*S_LEN + qi))*DM + h*HD + df*16 + lg*4]) = pk;
    }
  }
}

extern "C" void kernel_launch(void* const* d_in, const int* in_sizes, int n_in,
                              void* d_out, int out_size, void* d_ws, size_t ws_size,
                              hipStream_t stream){
  const float* hs = (const float*)d_in[0];
  const float* Wq = (const float*)d_in[3];
  const float* Wk = (const float*)d_in[4];
  const float* Wv = (const float*)d_in[5];
  const float* Wo = (const float*)d_in[6];

  uint8_t* base = (uint8_t*)d_ws;
  unsigned short* hsb  = (unsigned short*)base; base += (size_t)MTOK*DM*2;
  unsigned short* wqkv = (unsigned short*)base; base += (size_t)3*DM*DM*2;
  unsigned short* wob  = (unsigned short*)base; base += (size_t)DM*DM*2;
  unsigned short* Qr   = (unsigned short*)base; base += (size_t)MTOK*DM*2;
  unsigned short* Kr   = (unsigned short*)base; base += (size_t)MTOK*DM*2;
  unsigned short* Vp   = (unsigned short*)base; base += (size_t)MTOK*DM*2;
  unsigned short* AO   = (unsigned short*)base; base += (size_t)MTOK*DM*2;
  float* cosT = (float*)base;                   base += (size_t)S_LEN*64*4;
  float* sinT = (float*)base;                   base += (size_t)S_LEN*64*4;

  const int prep_blocks = (MTOK*DM/4 + 4*(DM*DM/4) + S_LEN*64 + 255) / 256;
  prep_kernel<<<prep_blocks, 256, 0, stream>>>(hs, Wq, Wk, Wv, Wo, hsb, wqkv, wob, cosT, sinT);

  hipFuncSetAttribute((const void*)gemm_2ph<3>,
                      hipFuncAttributeMaxDynamicSharedMemorySize, 81920);
  hipFuncSetAttribute((const void*)gemm_2ph<0>,
                      hipFuncAttributeMaxDynamicSharedMemorySize, 98304);

  // fused QKV + inline RoPE: 128x192 tiles, 1024 blocks = 2 rounds @ 2 blocks/CU
  gemm_2ph<3><<<1024, 512, 81920, stream>>>(hsb, wqkv, nullptr, Qr, Kr, Vp, cosT, sinT);

  attn_kernel<<<512, 256, 0, stream>>>(Qr, Kr, Vp, AO);

  // Wo: 128x256 tiles, 256 blocks = 1 round
  gemm_2ph<0><<<256, 512, 98304, stream>>>(AO, wob, (float*)d_out, nullptr, nullptr, nullptr, nullptr, nullptr);
}

// Round 20
// 235.739 us; speedup vs baseline: 1.6496x; 1.6496x over previous
//
#include <hip/hip_runtime.h>
#include <hip/hip_bf16.h>

#define S_LEN 2048
#define NH    16
#define HD    128
#define BHN   32      // B * NH
#define DM    2048
#define MTOK  4096    // B * S
#define NTK   32      // K / 64

typedef __attribute__((ext_vector_type(8))) short short8;
typedef __attribute__((ext_vector_type(4))) float f32x4;

__device__ __forceinline__ unsigned short f2bf(float x){
  union { __hip_bfloat16 h; unsigned short u; } c; c.h = __float2bfloat16(x); return c.u;
}
__device__ __forceinline__ float bf2f(unsigned short u){
  union { unsigned short u; __hip_bfloat16 h; } c; c.u = u; return __bfloat162float(c.h);
}

// ---------------- fused prep: hs cvt + 4 weight cvts + rope table ----------------
__global__ void prep_kernel(const float* __restrict__ hs, const float* __restrict__ Wq,
                            const float* __restrict__ Wk, const float* __restrict__ Wv,
                            const float* __restrict__ Wo,
                            unsigned short* __restrict__ hsb, unsigned short* __restrict__ wqkv,
                            unsigned short* __restrict__ wob,
                            float* __restrict__ cosT, float* __restrict__ sinT){
  const int NH4 = MTOK*DM/4;           // hs float4s
  const int NW4 = DM*DM/4;             // per-weight float4s (2^20)
  int gid = blockIdx.x*256 + threadIdx.x;
  if (gid < NH4){
    float4 v = reinterpret_cast<const float4*>(hs)[gid];
    ushort4 o;
    o.x = f2bf(v.x); o.y = f2bf(v.y); o.z = f2bf(v.z); o.w = f2bf(v.w);
    reinterpret_cast<ushort4*>(hsb)[gid] = o;
  } else if (gid < NH4 + 4*NW4){
    int k = gid - NH4;
    int which = k >> 20, j = k & (NW4 - 1);
    const float* src = (which==0) ? Wq : (which==1) ? Wk : (which==2) ? Wv : Wo;
    unsigned short* dst = (which<3) ? (wqkv + (size_t)which*DM*DM) : wob;
    float4 v = reinterpret_cast<const float4*>(src)[j];
    ushort4 o;
    o.x = f2bf(v.x); o.y = f2bf(v.y); o.z = f2bf(v.z); o.w = f2bf(v.w);
    reinterpret_cast<ushort4*>(dst)[j] = o;
  } else {
    int k = gid - NH4 - 4*NW4;
    if (k < S_LEN*64){
      int s = k >> 6, i = k & 63;
      float inv = powf(10000.f, -(float)i * (1.f/64.f));
      float ph = (float)s * inv;
      float sv, cv; sincosf(ph, &sv, &cv);
      cosT[k] = cv; sinT[k] = sv;
    }
  }
}

// ============ 128xBN whole-tile-dbuf GEMM, K=2048 ============
// MODE 3 (QKV): BN=384 (=3 heads), grid 512. Epilogue: V cols -> packed Vp from
//   acc; Q/K cols -> staging-LDS (dead after K-loop) -> rope pairing (d,d+64)
//   -> scatter. MODE 0 (Wo): BN=256, fp32 C, grid 256.
template<int MODE>
__global__ __launch_bounds__(512)
void gemm_2ph(const unsigned short* __restrict__ A, const unsigned short* __restrict__ B,
              float* __restrict__ C0, unsigned short* __restrict__ Cq,
              unsigned short* __restrict__ Ck, unsigned short* __restrict__ Cv,
              const float* __restrict__ cosT, const float* __restrict__ sinT){
  constexpr int BN   = (MODE==3) ? 384 : 256;
  constexpr int NJ   = BN/64;
  constexpr int BUFSZ = 16384 + BN*128;
  extern __shared__ unsigned char sm[];
  const int t = threadIdx.x;
  const int lane = t & 63, w = t >> 6;
  const int lr = lane & 15, lg = lane >> 4;
  const int wm = w >> 2, wn = w & 3;
  int bm, bn;
  if (MODE == 3){ int x = blockIdx.x & 7, i = blockIdx.x >> 3;
                  bn = x*2 + (i >> 5); bm = i & 31; }
  else          { bn = blockIdx.x & 7; bm = blockIdx.x >> 3; }
  const size_t rs = 4096;
  const unsigned char* Ab = (const unsigned char*)A + (size_t)bm*128*rs;
  const unsigned char* Bb = (const unsigned char*)B + (size_t)bn*BN*rs;
  const int r0 = t >> 3, c0 = t & 7;
  const int cs = (c0 ^ (r0 & 7)) << 4;

  auto stage = [&](int tkt){
    if (tkt >= NTK) return;
    unsigned char* hb = sm + (tkt & 1)*BUFSZ;
    const unsigned char* Bt = Bb + (size_t)tkt*128;
#pragma unroll
    for (int j=0;j<NJ;++j)
      __builtin_amdgcn_global_load_lds((const unsigned int*)(Bt + (size_t)(r0+64*j)*rs + cs),
          (unsigned int*)(hb + 16384 + (size_t)(t + 512*j)*16), 16, 0, 0);
    const unsigned char* At = Ab + (size_t)tkt*128;
    __builtin_amdgcn_global_load_lds((const unsigned int*)(At + (size_t)r0*rs + cs),
        (unsigned int*)(hb + t*16), 16, 0, 0);
    __builtin_amdgcn_global_load_lds((const unsigned int*)(At + (size_t)(r0+64)*rs + cs),
        (unsigned int*)(hb + 8192 + t*16), 16, 0, 0);
  };

  f32x4 acc[4][NJ] = {};

  stage(0);
  asm volatile("s_waitcnt vmcnt(0)" ::: "memory");
  __builtin_amdgcn_s_barrier();

  for (int g = 0; g < NTK; ++g){
    stage(g+1);
    const unsigned char* hb = sm + (g & 1)*BUFSZ;
    short8 af[8];
#pragma unroll
    for (int mi=0;mi<4;++mi){
      int row = wm*64 + mi*16 + lr;
      const unsigned char* rp = hb + row*128;
      int x = (row & 7) << 4;
#pragma unroll
      for (int ks=0;ks<2;++ks)
        af[mi*2+ks] = *reinterpret_cast<const short8*>(rp + (((ks*4+lg) << 4) ^ x));
    }
    short8 bfr[NJ*2];
#pragma unroll
    for (int nj=0;nj<NJ;++nj){
      int row = wn*(BN/4) + nj*16 + lr;
      const unsigned char* rp = hb + 16384 + row*128;
      int x = (row & 7) << 4;
#pragma unroll
      for (int ks=0;ks<2;++ks)
        bfr[nj*2+ks] = *reinterpret_cast<const short8*>(rp + (((ks*4+lg) << 4) ^ x));
    }
    __builtin_amdgcn_s_setprio(1);
#pragma unroll
    for (int mi=0;mi<4;++mi)
#pragma unroll
      for (int nj=0;nj<NJ;++nj){
        acc[mi][nj] = __builtin_amdgcn_mfma_f32_16x16x32_bf16(af[mi*2+0], bfr[nj*2+0], acc[mi][nj], 0,0,0);
        acc[mi][nj] = __builtin_amdgcn_mfma_f32_16x16x32_bf16(af[mi*2+1], bfr[nj*2+1], acc[mi][nj], 0,0,0);
      }
    __builtin_amdgcn_s_setprio(0);
    asm volatile("s_waitcnt vmcnt(0)" ::: "memory");
    __builtin_amdgcn_s_barrier();
  }

  if (MODE == 0){
#pragma unroll
    for (int mi=0;mi<4;++mi)
#pragma unroll
      for (int nj=0;nj<NJ;++nj){
        int col  = bn*BN + wn*(BN/4) + nj*16 + lr;
        int rowb = bm*128 + wm*64 + mi*16 + lg*4;
#pragma unroll
        for (int rr=0;rr<4;++rr)
          C0[(size_t)(rowb+rr)*DM + col] = acc[mi][nj][rr];
      }
  } else {
    // ---- V columns (col >= 4096): direct from acc to packed Vp ----
#pragma unroll
    for (int mi=0;mi<4;++mi)
#pragma unroll
      for (int nj=0;nj<NJ;++nj){
        int col  = bn*BN + wn*(BN/4) + nj*16 + lr;
        int rowb = bm*128 + wm*64 + mi*16 + lg*4;
        if (col >= 4096){
          int cc = col - 4096, h = cc >> 7, dd = cc & 127;
          ushort4 pk;
          pk.x = f2bf(acc[mi][nj][0]); pk.y = f2bf(acc[mi][nj][1]);
          pk.z = f2bf(acc[mi][nj][2]); pk.w = f2bf(acc[mi][nj][3]);
          int bb = rowb >> 11, s = rowb & 2047, kb = s >> 6, kvl = s & 63;
          *reinterpret_cast<ushort4*>(&Cv[(((size_t)((bb*16+h)*32 + kb)*128 + dd)<<6) + kvl]) = pk;
        }
      }
    // ---- Q/K columns: acc -> LDS [128][392] -> rope (d, d+64) -> scatter ----
    if (bn <= 10){
      unsigned short* S = reinterpret_cast<unsigned short*>(sm);  // 128*392*2 = 100352 B
#pragma unroll
      for (int mi=0;mi<4;++mi)
#pragma unroll
        for (int nj=0;nj<NJ;++nj){
          int col = bn*BN + wn*96 + nj*16 + lr;
          if (col < 4096){
            int cl = wn*96 + nj*16 + lr;
            int rl = wm*64 + mi*16 + lg*4;
#pragma unroll
            for (int rr=0;rr<4;++rr)
              S[(rl+rr)*392 + cl] = f2bf(acc[mi][nj][rr]);
          }
        }
      __syncthreads();
      const int nH = (bn < 10) ? 3 : 2;          // Q/K heads in this block
      const int items = (128*nH*16)/512;         // 12 or 8, exact
      for (int it=0; it<items; ++it){
        int idx = it*512 + t;
        int r   = idx / (nH*16);
        int rem = idx - r*(nH*16);
        int hb  = rem >> 4, c4 = rem & 15;
        int cl  = hb*128 + c4*4;
        ushort4 lo = *reinterpret_cast<const ushort4*>(&S[r*392 + cl]);
        ushort4 hi = *reinterpret_cast<const ushort4*>(&S[r*392 + cl + 64]);
        int row = bm*128 + r, bb = row >> 11, s = row & 2047;
        int h = bn*3 + hb;                       // global head 0..31
        const float* ct = cosT + s*64; const float* st = sinT + s*64;
        int f = c4*2;
        float ca0 = ct[f],    sa0 = st[f];
        float ca1 = ct[f+1],  sa1 = st[f+1];
        float cb0 = ct[32+f],   sb0 = st[32+f];
        float cb1 = ct[32+f+1], sb1 = st[32+f+1];
        float l0 = bf2f(lo.x), l1 = bf2f(lo.y), l2 = bf2f(lo.z), l3 = bf2f(lo.w);
        float h0 = bf2f(hi.x), h1 = bf2f(hi.y), h2 = bf2f(hi.z), h3 = bf2f(hi.w);
        ushort4 olo, ohi;
        olo.x = f2bf(l0*ca0 - h0*sa0); ohi.x = f2bf(h0*cb0 + l0*sb0);
        olo.y = f2bf(l1*ca0 - h1*sa0); ohi.y = f2bf(h1*cb0 + l1*sb0);
        olo.z = f2bf(l2*ca1 - h2*sa1); ohi.z = f2bf(h2*cb1 + l2*sb1);
        olo.w = f2bf(l3*ca1 - h3*sa1); ohi.w = f2bf(h3*cb1 + l3*sb1);
        unsigned short* dst = (h < 16) ? Cq : Ck;
        size_t base2 = (((size_t)(bb*16 + (h & 15))*2048 + s) << 7) + c4*4;
        *reinterpret_cast<ushort4*>(&dst[base2])      = olo;
        *reinterpret_cast<ushort4*>(&dst[base2 + 64]) = ohi;
      }
    }
  }
}

// ---------------- causal softcap flash attention (double-buffered LDS K/V) ----------------
__global__ __launch_bounds__(256, 2)
void attn_kernel(const unsigned short* __restrict__ Qr, const unsigned short* __restrict__ Kr,
                 const unsigned short* __restrict__ Vp, unsigned short* __restrict__ AO){
  extern __shared__ unsigned char sm[];             // 81920 B
  const int bid = blockIdx.x;                 // 512 = 16 qb * 32 bh
  const int qb  = (bid < 256) ? (15 - (bid >> 5)) : ((bid >> 5) - 8);
  const int bh  = bid & 31;
  const int t = threadIdx.x;
  const int w = t >> 6, lane = t & 63, lr = lane & 15, lg = lane >> 4;
  const int qbase = qb*128 + w*32;
  const int diag_w = (qbase + 31) >> 6;
  const int kmax = qb*2 + 1;
  const unsigned short* Qh = Qr + (size_t)bh*S_LEN*HD;
  const unsigned char*  Kg = (const unsigned char*)(Kr + (size_t)bh*S_LEN*HD);
  const unsigned char*  Vg = (const unsigned char*)Vp + (size_t)bh*32*16384;

  short8 qa[2][4];
#pragma unroll
  for (int f=0;f<2;++f)
#pragma unroll
    for (int kc=0;kc<4;++kc)
      qa[f][kc] = *reinterpret_cast<const short8*>(&Qh[(size_t)(qbase + f*16 + lr)*HD + kc*32 + lg*8]);

  float lsum[2] = {0.f, 0.f};
  f32x4 o[2][8] = {};

  const float PA = 0.12752783f;      // log2e*SCALE
  const float PB = -3.68975e-7f;     // -log2e*SCALE^3/2700
  const float PC = 1.28117e-12f;     // log2e*1.6460905e-7*SCALE^5
  const float PD = -43.2808512f;     // -30*log2e

  auto stage = [&](int tkt){
    if (tkt > kmax) return;
    const int d = tkt & 1;
    const unsigned char* Kt = Kg + (size_t)tkt*16384;
    const unsigned char* Vt = Vg + (size_t)tkt*16384;
    unsigned char* Kd = sm + d*16384;
    unsigned char* Vd = sm + 32768 + d*16384;
#pragma unroll
    for (int j=0;j<4;++j){
      unsigned int L  = (unsigned int)(w*4+j)*1024u + (unsigned int)lane*16u;
      unsigned int rK = L >> 8;
      unsigned int sK = (L & 255u) ^ ((rK & 15u) << 4);
      __builtin_amdgcn_global_load_lds((const unsigned int*)(Kt + (rK<<8) + sK),
          (unsigned int*)(Kd + (size_t)(w*4+j)*1024), 16, 0, 0);
      unsigned int rV = L >> 7;
      unsigned int sV = (L & 127u) ^ ((rV & 7u) << 4);
      __builtin_amdgcn_global_load_lds((const unsigned int*)(Vt + (rV<<7) + sV),
          (unsigned int*)(Vd + (size_t)(w*4+j)*1024), 16, 0, 0);
    }
  };

  unsigned char* Psb = sm + 65536 + w*4096;   // [32 rows][128B], XOR-swizzled

  stage(0);
  __syncthreads();

  for (int kb = 0; kb <= kmax; ++kb){
    stage(kb+1);
    const int d = kb & 1;
    const unsigned char* Kd = sm + d*16384;
    const unsigned char* Vd = sm + 32768 + d*16384;
    if (kb <= diag_w){
      f32x4 s[2][4] = {};
      __builtin_amdgcn_s_setprio(1);
#pragma unroll
      for (int nf=0;nf<4;++nf)
#pragma unroll
        for (int kc=0;kc<4;++kc){
          unsigned int byt = ((unsigned int)(nf*16+lr) << 8) + (((unsigned int)(kc*64 + lg*16)) ^ ((unsigned int)lr << 4));
          short8 kf = *reinterpret_cast<const short8*>(Kd + byt);
          s[0][nf] = __builtin_amdgcn_mfma_f32_16x16x32_bf16(kf, qa[0][kc], s[0][nf], 0,0,0);
          s[1][nf] = __builtin_amdgcn_mfma_f32_16x16x32_bf16(kf, qa[1][kc], s[1][nf], 0,0,0);
        }
      __builtin_amdgcn_s_setprio(0);
#pragma unroll
      for (int f=0;f<2;++f){
        const int prow = f*16 + lr;
        const unsigned int pswz = (unsigned int)(prow & 7) << 4;
#pragma unroll
        for (int nf=0;nf<4;++nf){
#pragma unroll
          for (int r=0;r<4;++r){
            float sv = s[f][nf][r];
            float u2 = sv*sv;
            float tt = fmaf(u2, PC, PB);
            tt = fmaf(u2, tt, PA);
            float p = __builtin_amdgcn_exp2f(fmaf(sv, tt, PD));
            if (kb == diag_w){
              int kvi = kb*64 + nf*16 + lg*4 + r;
              if (kvi > qbase + f*16 + lr) p = 0.f;
            }
            s[f][nf][r] = p;
            lsum[f] += p;
          }
          ushort4 pk;
          pk.x = f2bf(s[f][nf][0]); pk.y = f2bf(s[f][nf][1]);
          pk.z = f2bf(s[f][nf][2]); pk.w = f2bf(s[f][nf][3]);
          *reinterpret_cast<ushort4*>(Psb + prow*128 + (((unsigned int)(nf*32 + lg*8)) ^ pswz)) = pk;
        }
      }
      short8 pb[2][2];
#pragma unroll
      for (int f=0;f<2;++f){
        const int prow = f*16 + lr;
        const unsigned int pswz = (unsigned int)(prow & 7) << 4;
#pragma unroll
        for (int kc2=0;kc2<2;++kc2)
          pb[f][kc2] = *reinterpret_cast<const short8*>(Psb + prow*128 + (((unsigned int)(kc2*64 + lg*16)) ^ pswz));
      }
      __builtin_amdgcn_s_setprio(1);
#pragma unroll
      for (int df=0;df<8;++df)
#pragma unroll
        for (int kc2=0;kc2<2;++kc2){
          unsigned int byt = ((unsigned int)(df*16+lr) << 7) + (((unsigned int)(kc2*64 + lg*16)) ^ ((unsigned int)(lr&7) << 4));
          short8 vb = *reinterpret_cast<const short8*>(Vd + byt);
          o[0][df] = __builtin_amdgcn_mfma_f32_16x16x32_bf16(vb, pb[0][kc2], o[0][df], 0,0,0);
          o[1][df] = __builtin_amdgcn_mfma_f32_16x16x32_bf16(vb, pb[1][kc2], o[1][df], 0,0,0);
        }
      __builtin_amdgcn_s_setprio(0);
    }
    __syncthreads();
  }
#pragma unroll
  for (int f=0;f<2;++f){
    lsum[f] += __shfl_xor(lsum[f], 16);
    lsum[f] += __shfl_xor(lsum[f], 32);
  }
  const int bb = bh >> 4, h = bh & 15;
#pragma unroll
  for (int f=0;f<2;++f){
    const float inv = 1.f / lsum[f];
    const int qi = qbase + f*16 + lr;
#pragma unroll
    for (int df=0;df<8;++df){
      ushort4 pk;
      pk.x = f2bf(o[f][df][0] * inv); pk.y = f2bf(o[f][df][1] * inv);
      pk.z = f2bf(o[f][df][2] * inv); pk.w = f2bf(o[f][df][3] * inv);
      *reinterpret_cast<ushort4*>(&AO[((size_t)(bb*S_LEN + qi))*DM + h*HD + df*16 + lg*4]) = pk;
    }
  }
}

extern "C" void kernel_launch(void* const* d_in, const int* in_sizes, int n_in,
                              void* d_out, int out_size, void* d_ws, size_t ws_size,
                              hipStream_t stream){
  const float* hs = (const float*)d_in[0];
  const float* Wq = (const float*)d_in[3];
  const float* Wk = (const float*)d_in[4];
  const float* Wv = (const float*)d_in[5];
  const float* Wo = (const float*)d_in[6];

  uint8_t* base = (uint8_t*)d_ws;
  unsigned short* hsb  = (unsigned short*)base; base += (size_t)MTOK*DM*2;
  unsigned short* wqkv = (unsigned short*)base; base += (size_t)3*DM*DM*2;
  unsigned short* wob  = (unsigned short*)base; base += (size_t)DM*DM*2;
  unsigned short* Qr   = (unsigned short*)base; base += (size_t)MTOK*DM*2;
  unsigned short* Kr   = (unsigned short*)base; base += (size_t)MTOK*DM*2;
  unsigned short* Vp   = (unsigned short*)base; base += (size_t)MTOK*DM*2;
  unsigned short* AO   = (unsigned short*)base; base += (size_t)MTOK*DM*2;
  float* cosT = (float*)base;                   base += (size_t)S_LEN*64*4;
  float* sinT = (float*)base;                   base += (size_t)S_LEN*64*4;

  const int prep_blocks = (MTOK*DM/4 + 4*(DM*DM/4) + S_LEN*64 + 255) / 256;
  prep_kernel<<<prep_blocks, 256, 0, stream>>>(hs, Wq, Wk, Wv, Wo, hsb, wqkv, wob, cosT, sinT);

  hipFuncSetAttribute((const void*)gemm_2ph<3>,
                      hipFuncAttributeMaxDynamicSharedMemorySize, 131072);
  hipFuncSetAttribute((const void*)gemm_2ph<0>,
                      hipFuncAttributeMaxDynamicSharedMemorySize, 98304);
  hipFuncSetAttribute((const void*)attn_kernel,
                      hipFuncAttributeMaxDynamicSharedMemorySize, 81920);

  // fused QKV + inline RoPE: [4096,2048] x [6144,2048]^T, 128x384, 512 blocks
  gemm_2ph<3><<<512, 512, 131072, stream>>>(hsb, wqkv, nullptr, Qr, Kr, Vp, cosT, sinT);

  attn_kernel<<<512, 256, 81920, stream>>>(Qr, Kr, Vp, AO);

  // Wo: [4096,2048] x [2048,2048]^T, 128x256, 256 blocks
  gemm_2ph<0><<<256, 512, 98304, stream>>>(AO, wob, (float*)d_out, nullptr, nullptr, nullptr, nullptr, nullptr);
}